// Round 1
// baseline (3778.739 us; speedup 1.0000x reference)
//
#include <hip/hip_runtime.h>
#include <hip/hip_bf16.h>

// Problem constants
#define BB 4
#define SS 1024
#define DD 1024
#define HH 16
#define DKH 64
#define EPS_LN 1e-6f

#define M_ROWS 4096   // B*S
#define N_COLS 1024   // H*DK
#define K_DIM  1024   // D

// ---------------------------------------------------------------------------
// Complex GEMM: Y = X @ W^T (optionally * scale, optionally + residual)
// X: [M,K] complex (xr,xi), W: [N,K] complex (wr,wi), Y: [M,N] complex
// Tile 64x64, 256 threads, 4x4 complex per thread, K-chunk 16.
// ---------------------------------------------------------------------------
__global__ __launch_bounds__(256) void cgemm_nt(
    const float* __restrict__ xr, const float* __restrict__ xi,
    const float* __restrict__ wr, const float* __restrict__ wi,
    float* __restrict__ yr, float* __restrict__ yi,
    float scale,
    const float* __restrict__ resr, const float* __restrict__ resi)
{
    // LDS: tiles stored transposed [k][m] / [k][n], stride 68 keeps float4
    // alignment (68*4=272B, 16B-aligned) and 2-way-max bank aliasing (free).
    __shared__ float xsr[16][68], xsi[16][68], wsr[16][68], wsi[16][68];

    const int tid = threadIdx.x;
    const int ti  = tid >> 4;        // 0..15, m direction
    const int tj  = tid & 15;        // 0..15, n direction
    const int m0  = blockIdx.y * 64;
    const int n0  = blockIdx.x * 64;
    const int lrow = tid >> 2;       // 0..63 row within tile
    const int lc4  = (tid & 3) * 4;  // k offset of this thread's float4

    float accr[4][4] = {{0.f}}, acci[4][4] = {{0.f}};

    for (int k0 = 0; k0 < K_DIM; k0 += 16) {
        const size_t xoff = (size_t)(m0 + lrow) * K_DIM + k0 + lc4;
        const size_t woff = (size_t)(n0 + lrow) * K_DIM + k0 + lc4;
        float4 ax = *(const float4*)(xr + xoff);
        float4 bx = *(const float4*)(xi + xoff);
        float4 aw = *(const float4*)(wr + woff);
        float4 bw = *(const float4*)(wi + woff);
        __syncthreads();   // previous chunk's compute done reading LDS
        xsr[lc4+0][lrow]=ax.x; xsr[lc4+1][lrow]=ax.y; xsr[lc4+2][lrow]=ax.z; xsr[lc4+3][lrow]=ax.w;
        xsi[lc4+0][lrow]=bx.x; xsi[lc4+1][lrow]=bx.y; xsi[lc4+2][lrow]=bx.z; xsi[lc4+3][lrow]=bx.w;
        wsr[lc4+0][lrow]=aw.x; wsr[lc4+1][lrow]=aw.y; wsr[lc4+2][lrow]=aw.z; wsr[lc4+3][lrow]=aw.w;
        wsi[lc4+0][lrow]=bw.x; wsi[lc4+1][lrow]=bw.y; wsi[lc4+2][lrow]=bw.z; wsi[lc4+3][lrow]=bw.w;
        __syncthreads();
        #pragma unroll
        for (int kk = 0; kk < 16; ++kk) {
            float4 q4 = *(const float4*)&xsr[kk][ti*4];
            float4 p4 = *(const float4*)&xsi[kk][ti*4];
            float4 b4 = *(const float4*)&wsr[kk][tj*4];
            float4 c4 = *(const float4*)&wsi[kk][tj*4];
            const float xrv[4] = {q4.x,q4.y,q4.z,q4.w};
            const float xiv[4] = {p4.x,p4.y,p4.z,p4.w};
            const float wrv[4] = {b4.x,b4.y,b4.z,b4.w};
            const float wiv[4] = {c4.x,c4.y,c4.z,c4.w};
            #pragma unroll
            for (int a = 0; a < 4; ++a) {
                #pragma unroll
                for (int b = 0; b < 4; ++b) {
                    accr[a][b] = fmaf(xrv[a],  wrv[b], accr[a][b]);
                    accr[a][b] = fmaf(-xiv[a], wiv[b], accr[a][b]);
                    acci[a][b] = fmaf(xrv[a],  wiv[b], acci[a][b]);
                    acci[a][b] = fmaf(xiv[a],  wrv[b], acci[a][b]);
                }
            }
        }
    }

    // Epilogue: scale, optional residual, float4 stores
    #pragma unroll
    for (int a = 0; a < 4; ++a) {
        const size_t row = (size_t)(m0 + ti*4 + a) * N_COLS + n0 + tj*4;
        float4 vr, vi;
        vr.x = accr[a][0]*scale; vr.y = accr[a][1]*scale;
        vr.z = accr[a][2]*scale; vr.w = accr[a][3]*scale;
        vi.x = acci[a][0]*scale; vi.y = acci[a][1]*scale;
        vi.z = acci[a][2]*scale; vi.w = acci[a][3]*scale;
        if (resr) {
            float4 rr = *(const float4*)(resr + row);
            float4 ri = *(const float4*)(resi + row);
            vr.x += rr.x; vr.y += rr.y; vr.z += rr.z; vr.w += rr.w;
            vi.x += ri.x; vi.y += ri.y; vi.z += ri.z; vi.w += ri.w;
        }
        *(float4*)(yr + row) = vr;
        *(float4*)(yi + row) = vi;
    }
}

// ---------------------------------------------------------------------------
// Attention: per block = (b, h, 32 q-rows). Streams K/V in 32-row tiles.
// Exact MagMinMaxNorm via decomposition o = (A - mn*P)/(mx - mn),
//   A = sum_k attn_k * v_k,  P = sum_k (attn_k/|attn_k|) * v_k,
// with mn/mx tracked online as uint-bit min/max (mag >= 0).
// ---------------------------------------------------------------------------
#define TQ 32
#define TK 32
#define RSTR 130   // floats per LDS row of 64 complex (65 complex, padded)
#define ASTR 66    // floats per attn LDS row (33 complex)

__global__ __launch_bounds__(256) void attn_kernel(
    const float* __restrict__ qp_r, const float* __restrict__ qp_i,
    const float* __restrict__ kp_r, const float* __restrict__ kp_i,
    const float* __restrict__ vp_r, const float* __restrict__ vp_i,
    float* __restrict__ o_r, float* __restrict__ o_i)
{
    __shared__ float qs[TQ * RSTR];
    __shared__ float ks[TK * RSTR];
    __shared__ float vs[TK * RSTR];
    __shared__ float as[TQ * ASTR];
    __shared__ float ims[TQ * 33];
    __shared__ unsigned mnb[TQ], mxb[TQ];

    const int tid = threadIdx.x;
    const int qt = blockIdx.x, h = blockIdx.y, b = blockIdx.z;

    const size_t base_q  = ((size_t)(b * SS + qt * TQ)) * DD + h * DKH;
    const size_t base_kv = ((size_t)(b * SS)) * DD + h * DKH;

    // load q tile [32 rows x 64 complex] interleaved
    for (int idx = tid; idx < TQ * 64; idx += 256) {
        const int qq = idx >> 6, d = idx & 63;
        const size_t off = base_q + (size_t)qq * DD + d;
        qs[qq * RSTR + 2*d]     = qp_r[off];
        qs[qq * RSTR + 2*d + 1] = qp_i[off];
    }
    if (tid < TQ) { mnb[tid] = 0x7f800000u; mxb[tid] = 0u; }

    // phase-3 ownership: dv = tid&63, q rows g+4j
    const int dv = tid & 63;
    const int g  = tid >> 6;
    float Ar[8] = {0.f}, Ai[8] = {0.f}, Pr[8] = {0.f}, Pi[8] = {0.f};

    // phase-2 ownership: one q row, 4 consecutive k
    const int qq2 = tid >> 3;
    const int kb  = (tid & 7) * 4;

    for (int kt = 0; kt < SS / TK; ++kt) {
        __syncthreads();   // prev phase3 done reading ks/vs/as
        // load K,V tile
        for (int idx = tid; idx < TK * 64; idx += 256) {
            const int kk = idx >> 6, d = idx & 63;
            const size_t off = base_kv + (size_t)(kt * TK + kk) * DD + d;
            ks[kk * RSTR + 2*d]     = kp_r[off];
            ks[kk * RSTR + 2*d + 1] = kp_i[off];
            vs[kk * RSTR + 2*d]     = vp_r[off];
            vs[kk * RSTR + 2*d + 1] = vp_i[off];
        }
        __syncthreads();

        // phase 2: attn block [32q x 32k], 4 cells per thread
        float ar[4] = {0.f}, ai[4] = {0.f};
        for (int d2 = 0; d2 < 64; ++d2) {
            const float qrv = qs[qq2 * RSTR + 2*d2];
            const float qiv = qs[qq2 * RSTR + 2*d2 + 1];
            #pragma unroll
            for (int c = 0; c < 4; ++c) {
                const float krv = ks[(kb + c) * RSTR + 2*d2];
                const float kiv = ks[(kb + c) * RSTR + 2*d2 + 1];
                ar[c] = fmaf(qrv, krv, ar[c]);
                ar[c] = fmaf(-qiv, kiv, ar[c]);
                ai[c] = fmaf(qrv, kiv, ai[c]);
                ai[c] = fmaf(qiv, krv, ai[c]);
            }
        }
        unsigned lmn = 0x7f800000u, lmx = 0u;
        #pragma unroll
        for (int c = 0; c < 4; ++c) {
            const float mag = sqrtf(ar[c]*ar[c] + ai[c]*ai[c]);
            const float im_ = mag > 0.f ? 1.f / mag : 0.f;
            as[qq2 * ASTR + 2*(kb + c)]     = ar[c];
            as[qq2 * ASTR + 2*(kb + c) + 1] = ai[c];
            ims[qq2 * 33 + kb + c] = im_;
            const unsigned mb = __float_as_uint(mag);
            lmn = lmn < mb ? lmn : mb;
            lmx = lmx > mb ? lmx : mb;
        }
        atomicMin(&mnb[qq2], lmn);
        atomicMax(&mxb[qq2], lmx);
        __syncthreads();

        // phase 3: accumulate A and P
        for (int kk = 0; kk < TK; ++kk) {
            const float vrv = vs[kk * RSTR + 2*dv];
            const float viv = vs[kk * RSTR + 2*dv + 1];
            #pragma unroll
            for (int j = 0; j < 8; ++j) {
                const int q = g + 4*j;
                const float arv = as[q * ASTR + 2*kk];
                const float aiv = as[q * ASTR + 2*kk + 1];
                const float imv = ims[q * 33 + kk];
                const float tr = arv * vrv - aiv * viv;
                const float ti2 = arv * viv + aiv * vrv;
                Ar[j] += tr;  Ai[j] += ti2;
                Pr[j] = fmaf(tr, imv, Pr[j]);
                Pi[j] = fmaf(ti2, imv, Pi[j]);
            }
        }
    }
    __syncthreads();

    // epilogue: o = (A - mn*P) / (mx - mn)
    #pragma unroll
    for (int j = 0; j < 8; ++j) {
        const int q = g + 4*j;
        const float mn = __uint_as_float(mnb[q]);
        const float mx = __uint_as_float(mxb[q]);
        const float dns = mx - mn;
        const float invd = dns > 0.f ? 1.f / dns : 0.f;
        const size_t off = base_q + (size_t)q * DD + dv;
        o_r[off] = (Ar[j] - mn * Pr[j]) * invd;
        o_i[off] = (Ai[j] - mn * Pi[j]) * invd;
    }
}

// ---------------------------------------------------------------------------
// Complex covariance-whitening layernorm, one wave per (b,s) row.
// ---------------------------------------------------------------------------
__global__ __launch_bounds__(256) void ln_kernel(
    const float* __restrict__ xr, const float* __restrict__ xi,
    const float* __restrict__ g_rr, const float* __restrict__ g_ri,
    const float* __restrict__ g_ii,
    const float* __restrict__ b_r, const float* __restrict__ b_i,
    float* __restrict__ out)
{
    const int lane = threadIdx.x & 63;
    const int wave = threadIdx.x >> 6;
    const int row  = blockIdx.x * 4 + wave;   // 0..4095
    const float* pr = xr + (size_t)row * DD;
    const float* pi = xi + (size_t)row * DD;

    float r[16], im[16];
    float sr = 0.f, si = 0.f;
    #pragma unroll
    for (int j = 0; j < 16; ++j) {
        r[j]  = pr[lane + 64*j];
        im[j] = pi[lane + 64*j];
        sr += r[j]; si += im[j];
    }
    #pragma unroll
    for (int o = 32; o; o >>= 1) { sr += __shfl_xor(sr, o); si += __shfl_xor(si, o); }
    const float mr = sr * (1.f / DD), mi = si * (1.f / DD);

    float srr = 0.f, sii = 0.f, sri = 0.f;
    #pragma unroll
    for (int j = 0; j < 16; ++j) {
        const float a = r[j] - mr, c = im[j] - mi;
        srr = fmaf(a, a, srr); sii = fmaf(c, c, sii); sri = fmaf(a, c, sri);
    }
    #pragma unroll
    for (int o = 32; o; o >>= 1) {
        srr += __shfl_xor(srr, o); sii += __shfl_xor(sii, o); sri += __shfl_xor(sri, o);
    }
    const float Vrr = srr * (1.f / DD) + EPS_LN;
    const float Vii = sii * (1.f / DD) + EPS_LN;
    const float Vri = sri * (1.f / DD);
    const float s  = sqrtf(Vrr * Vii - Vri * Vri);
    const float t  = sqrtf(Vrr + Vii + 2.f * s);
    const float inv = 1.f / (s * t);
    const float Wrr = (Vii + s) * inv;
    const float Wii = (Vrr + s) * inv;
    const float Wri = -Vri * inv;

    #pragma unroll
    for (int j = 0; j < 16; ++j) {
        const int d = lane + 64*j;
        const float a = r[j] - mr, c = im[j] - mi;
        const float or_ = Wrr * a + Wri * c;
        const float oi_ = Wri * a + Wii * c;
        out[(size_t)row * DD + d] = g_rr[d]*or_ + g_ri[d]*oi_ + b_r[d];
        out[(size_t)(M_ROWS) * DD + (size_t)row * DD + d] = g_ri[d]*or_ + g_ii[d]*oi_ + b_i[d];
    }
}

// ---------------------------------------------------------------------------
extern "C" void kernel_launch(void* const* d_in, const int* in_sizes, int n_in,
                              void* d_out, int out_size, void* d_ws, size_t ws_size,
                              hipStream_t stream) {
    const float* q_r  = (const float*)d_in[0];
    const float* q_i  = (const float*)d_in[1];
    const float* k_r  = (const float*)d_in[2];
    const float* k_i  = (const float*)d_in[3];
    const float* v_r  = (const float*)d_in[4];
    const float* v_i  = (const float*)d_in[5];
    const float* wq_r = (const float*)d_in[6];
    const float* wq_i = (const float*)d_in[7];
    const float* wk_r = (const float*)d_in[8];
    const float* wk_i = (const float*)d_in[9];
    const float* wv_r = (const float*)d_in[10];
    const float* wv_i = (const float*)d_in[11];
    const float* fc_r = (const float*)d_in[12];
    const float* fc_i = (const float*)d_in[13];
    const float* g_rr = (const float*)d_in[14];
    const float* g_ri = (const float*)d_in[15];
    const float* g_ii = (const float*)d_in[16];
    const float* b_r  = (const float*)d_in[17];
    const float* b_i  = (const float*)d_in[18];
    float* out = (float*)d_out;

    float* ws = (float*)d_ws;
    const size_t NE = (size_t)M_ROWS * N_COLS;  // 4096*1024
    float* qpr = ws + 0*NE;
    float* qpi = ws + 1*NE;
    float* kpr = ws + 2*NE;
    float* kpi = ws + 3*NE;
    float* vpr = ws + 4*NE;
    float* vpi = ws + 5*NE;
    float* opr = ws + 6*NE;
    float* opi = ws + 7*NE;
    // fc output reuses the dead Q-projection buffers
    float* fr = qpr;
    float* fi = qpi;

    const dim3 gblk(N_COLS / 64, M_ROWS / 64);  // (16, 64)

    // QKV projections (q gets 1/sqrt(DK) folded in)
    cgemm_nt<<<gblk, 256, 0, stream>>>(q_r, q_i, wq_r, wq_i, qpr, qpi, 0.125f, nullptr, nullptr);
    cgemm_nt<<<gblk, 256, 0, stream>>>(k_r, k_i, wk_r, wk_i, kpr, kpi, 1.0f, nullptr, nullptr);
    cgemm_nt<<<gblk, 256, 0, stream>>>(v_r, v_i, wv_r, wv_i, vpr, vpi, 1.0f, nullptr, nullptr);

    // fused attention + MagMinMaxNorm
    attn_kernel<<<dim3(SS / TQ, HH, BB), 256, 0, stream>>>(qpr, qpi, kpr, kpi, vpr, vpi, opr, opi);

    // output projection + residual
    cgemm_nt<<<gblk, 256, 0, stream>>>(opr, opi, fc_r, fc_i, fr, fi, 1.0f, q_r, q_i);

    // complex layernorm -> d_out [2,B,S,D]
    ln_kernel<<<M_ROWS / 4, 256, 0, stream>>>(fr, fi, g_rr, g_ri, g_ii, b_r, b_i, out);
}

// Round 2
// 2012.280 us; speedup vs baseline: 1.8778x; 1.8778x over previous
//
#include <hip/hip_runtime.h>
#include <hip/hip_bf16.h>

// Problem constants
#define BB 4
#define SS 1024
#define DD 1024
#define HH 16
#define DKH 64
#define EPS_LN 1e-6f

#define M_ROWS 4096   // B*S
#define N_COLS 1024   // H*DK
#define K_DIM  1024   // D

typedef float  floatx4 __attribute__((ext_vector_type(4)));
typedef short  shortx8 __attribute__((ext_vector_type(8)));
#define MFMA16(a, b, c) __builtin_amdgcn_mfma_f32_16x16x32_bf16(a, b, c, 0, 0, 0)

// float -> bf16 (RNE) bit pattern
__device__ inline ushort f2b(float x) {
    union { float f; unsigned u; } a; a.f = x;
    unsigned r = (a.u + 0x7fffu + ((a.u >> 16) & 1u)) >> 16;
    return (ushort)r;
}

// negate a bf16x8 fragment (flip sign bits)
__device__ inline shortx8 negf(shortx8 x) {
    shortx8 r;
    #pragma unroll
    for (int i = 0; i < 8; ++i) r[i] = (short)(x[i] ^ (short)0x8000);
    return r;
}

// ---------------------------------------------------------------------------
// Complex GEMM: Y = X @ W^T, fp32 compute.
// mode 0: fp32 out (+ optional residual)  [used for fc]
// mode 1: bf16 QK pack  [row][h][re64|im64]          (scale applied)
// mode 2: bf16 V pack, transposed: [(b*H+h)*64+dv][t*64 + (s&31)] = vr, +32 = vi
// ---------------------------------------------------------------------------
__global__ __launch_bounds__(256) void cgemm_nt(
    const float* __restrict__ xr, const float* __restrict__ xi,
    const float* __restrict__ wr, const float* __restrict__ wi,
    float* __restrict__ yr, float* __restrict__ yi,
    ushort* __restrict__ pk,
    float scale,
    const float* __restrict__ resr, const float* __restrict__ resi,
    int mode)
{
    __shared__ float xsr[16][68], xsi[16][68], wsr[16][68], wsi[16][68];

    const int tid = threadIdx.x;
    const int ti  = tid >> 4;        // 0..15, m direction
    const int tj  = tid & 15;        // 0..15, n direction
    const int m0  = blockIdx.y * 64;
    const int n0  = blockIdx.x * 64;
    const int lrow = tid >> 2;       // 0..63 row within tile
    const int lc4  = (tid & 3) * 4;  // k offset of this thread's float4

    float accr[4][4] = {{0.f}}, acci[4][4] = {{0.f}};

    for (int k0 = 0; k0 < K_DIM; k0 += 16) {
        const size_t xoff = (size_t)(m0 + lrow) * K_DIM + k0 + lc4;
        const size_t woff = (size_t)(n0 + lrow) * K_DIM + k0 + lc4;
        float4 ax = *(const float4*)(xr + xoff);
        float4 bx = *(const float4*)(xi + xoff);
        float4 aw = *(const float4*)(wr + woff);
        float4 bw = *(const float4*)(wi + woff);
        __syncthreads();
        xsr[lc4+0][lrow]=ax.x; xsr[lc4+1][lrow]=ax.y; xsr[lc4+2][lrow]=ax.z; xsr[lc4+3][lrow]=ax.w;
        xsi[lc4+0][lrow]=bx.x; xsi[lc4+1][lrow]=bx.y; xsi[lc4+2][lrow]=bx.z; xsi[lc4+3][lrow]=bx.w;
        wsr[lc4+0][lrow]=aw.x; wsr[lc4+1][lrow]=aw.y; wsr[lc4+2][lrow]=aw.z; wsr[lc4+3][lrow]=aw.w;
        wsi[lc4+0][lrow]=bw.x; wsi[lc4+1][lrow]=bw.y; wsi[lc4+2][lrow]=bw.z; wsi[lc4+3][lrow]=bw.w;
        __syncthreads();
        #pragma unroll
        for (int kk = 0; kk < 16; ++kk) {
            float4 q4 = *(const float4*)&xsr[kk][ti*4];
            float4 p4 = *(const float4*)&xsi[kk][ti*4];
            float4 b4 = *(const float4*)&wsr[kk][tj*4];
            float4 c4 = *(const float4*)&wsi[kk][tj*4];
            const float xrv[4] = {q4.x,q4.y,q4.z,q4.w};
            const float xiv[4] = {p4.x,p4.y,p4.z,p4.w};
            const float wrv[4] = {b4.x,b4.y,b4.z,b4.w};
            const float wiv[4] = {c4.x,c4.y,c4.z,c4.w};
            #pragma unroll
            for (int a = 0; a < 4; ++a) {
                #pragma unroll
                for (int b = 0; b < 4; ++b) {
                    accr[a][b] = fmaf(xrv[a],  wrv[b], accr[a][b]);
                    accr[a][b] = fmaf(-xiv[a], wiv[b], accr[a][b]);
                    acci[a][b] = fmaf(xrv[a],  wiv[b], acci[a][b]);
                    acci[a][b] = fmaf(xiv[a],  wrv[b], acci[a][b]);
                }
            }
        }
    }

    if (mode == 0) {
        #pragma unroll
        for (int a = 0; a < 4; ++a) {
            const size_t row = (size_t)(m0 + ti*4 + a) * N_COLS + n0 + tj*4;
            float4 vr, vi;
            vr.x = accr[a][0]*scale; vr.y = accr[a][1]*scale;
            vr.z = accr[a][2]*scale; vr.w = accr[a][3]*scale;
            vi.x = acci[a][0]*scale; vi.y = acci[a][1]*scale;
            vi.z = acci[a][2]*scale; vi.w = acci[a][3]*scale;
            if (resr) {
                float4 rr = *(const float4*)(resr + row);
                float4 ri = *(const float4*)(resi + row);
                vr.x += rr.x; vr.y += rr.y; vr.z += rr.z; vr.w += rr.w;
                vi.x += ri.x; vi.y += ri.y; vi.z += ri.z; vi.w += ri.w;
            }
            *(float4*)(yr + row) = vr;
            *(float4*)(yi + row) = vi;
        }
    } else if (mode == 1) {
        const int hh = n0 >> 6;   // n0 is 64-aligned; whole tile is one head
        #pragma unroll
        for (int a = 0; a < 4; ++a) {
            const int row = m0 + ti*4 + a;
            ushort4 ur, ui;
            ur.x = f2b(accr[a][0]*scale); ur.y = f2b(accr[a][1]*scale);
            ur.z = f2b(accr[a][2]*scale); ur.w = f2b(accr[a][3]*scale);
            ui.x = f2b(acci[a][0]*scale); ui.y = f2b(acci[a][1]*scale);
            ui.z = f2b(acci[a][2]*scale); ui.w = f2b(acci[a][3]*scale);
            ushort* p = pk + (size_t)row * 2048 + hh * 128 + tj * 4;
            *(ushort4*)(p)      = ur;
            *(ushort4*)(p + 64) = ui;
        }
    } else {
        const int hh = n0 >> 6;
        #pragma unroll
        for (int a = 0; a < 4; ++a) {
            const int row = m0 + ti*4 + a;
            const int bb = row >> 10, s = row & 1023;
            const int tt = (s >> 5) * 64 + (s & 31);
            #pragma unroll
            for (int c = 0; c < 4; ++c) {
                const int dv = tj*4 + c;
                ushort* vp = pk + ((size_t)((bb*HH + hh)*64 + dv)) * 2048 + tt;
                vp[0]  = f2b(accr[a][c]*scale);
                vp[32] = f2b(acci[a][c]*scale);
            }
        }
    }
}

// ---------------------------------------------------------------------------
// MFMA attention + exact streamed MagMinMaxNorm.
//   attn_r = [qr,qi]·[kr,-ki]^T   attn_i = [qi,qr]·[kr,ki]^T   (K=128)
//   o = (A - mn*P)/(mx - mn);  A = sum attn*v,  P = sum (attn/|attn|)*v
// Per block: (b, h, 32 q rows); 4 waves. TK=32 streamed.
// Wave w: QK^T subtile (qt=w&1, kt=w>>1); AV dv-tile = w.
// ---------------------------------------------------------------------------
#define ASTR2 88   // bf16 stride: 176B rows -> 16B-aligned b128, <=2-way read conflicts

__global__ __launch_bounds__(256) void attn_mfma(
    const ushort* __restrict__ qpk, const ushort* __restrict__ kpk,
    const ushort* __restrict__ vpk,
    float* __restrict__ o_r, float* __restrict__ o_i)
{
    __shared__ __align__(16) ushort A1[32 * ASTR2];
    __shared__ __align__(16) ushort P1[32 * ASTR2];
    __shared__ unsigned mnb[32], mxb[32];

    const int tid  = threadIdx.x;
    const int wave = tid >> 6, lane = tid & 63;
    const int l15  = lane & 15, quad = lane >> 4;
    const int qt_w = wave & 1, kt_w = wave >> 1;
    const int qtile = blockIdx.x, h = blockIdx.y, b = blockIdx.z;
    const size_t qrow0 = (size_t)b * SS + (size_t)qtile * 32;

    if (tid < 32) { mnb[tid] = 0x7f800000u; mxb[tid] = 0u; }

    // Q fragments (A-operand): row = qt_w*16+l15, k = quad*8+j over d
    const ushort* qb = qpk + (qrow0 + qt_w*16 + l15) * 2048 + h * 128 + quad * 8;
    shortx8 Aq[4];
    #pragma unroll
    for (int f = 0; f < 4; ++f) Aq[f] = *(const shortx8*)(qb + f * 32);

    floatx4 accAor[2], accAoi[2], accPor[2], accPoi[2];
    #pragma unroll
    for (int qt = 0; qt < 2; ++qt) {
        accAor[qt] = (floatx4){0.f,0.f,0.f,0.f};
        accAoi[qt] = (floatx4){0.f,0.f,0.f,0.f};
        accPor[qt] = (floatx4){0.f,0.f,0.f,0.f};
        accPoi[qt] = (floatx4){0.f,0.f,0.f,0.f};
    }
    float rmn[4] = {1e30f,1e30f,1e30f,1e30f};
    float rmx[4] = {0.f,0.f,0.f,0.f};

    const ushort* kb0 = kpk + ((size_t)b * SS + kt_w*16 + l15) * 2048 + h * 128 + quad * 8;
    const ushort* vb0 = vpk + (((size_t)(b*HH + h)) * 64 + wave*16 + l15) * 2048 + quad * 8;

    for (int kt0 = 0; kt0 < SS; kt0 += 32) {
        // ---- QK^T on this wave's 16x16 subtile (both real & imag) ----
        const ushort* kb = kb0 + (size_t)kt0 * 2048;
        shortx8 K0 = *(const shortx8*)(kb);
        shortx8 K1 = *(const shortx8*)(kb + 32);
        shortx8 K2 = *(const shortx8*)(kb + 64);
        shortx8 K3 = *(const shortx8*)(kb + 96);
        shortx8 N2 = negf(K2), N3 = negf(K3);
        floatx4 cr = (floatx4){0.f,0.f,0.f,0.f};
        floatx4 ci = (floatx4){0.f,0.f,0.f,0.f};
        cr = MFMA16(Aq[0], K0, cr); cr = MFMA16(Aq[1], K1, cr);
        cr = MFMA16(Aq[2], N2, cr); cr = MFMA16(Aq[3], N3, cr);   // qr·kr − qi·ki
        ci = MFMA16(Aq[2], K0, ci); ci = MFMA16(Aq[3], K1, ci);
        ci = MFMA16(Aq[0], K2, ci); ci = MFMA16(Aq[1], K3, ci);   // qi·kr + qr·ki

        __syncthreads();   // prior iteration's A1/P1 reads complete
        #pragma unroll
        for (int r = 0; r < 4; ++r) {
            const float ar = cr[r], ai = ci[r];
            const float mag = sqrtf(fmaf(ar, ar, ai * ai));
            const float im  = mag > 0.f ? 1.f / mag : 0.f;
            rmn[r] = fminf(rmn[r], mag);
            rmx[r] = fmaxf(rmx[r], mag);
            const int q = qt_w*16 + quad*4 + r;     // C row = quad*4+reg
            const int k = kt_w*16 + l15;            // C col = lane&15
            A1[q*ASTR2 + k]      = f2b(ar);
            A1[q*ASTR2 + 32 + k] = f2b(ai);
            P1[q*ASTR2 + k]      = f2b(ar * im);
            P1[q*ASTR2 + 32 + k] = f2b(ai * im);
        }
        __syncthreads();

        // ---- A·V and P·V accumulate (this wave's 16 dv columns) ----
        const ushort* vb = vb0 + (kt0 >> 5) * 64;
        shortx8 Vr = *(const shortx8*)(vb);
        shortx8 Vi = *(const shortx8*)(vb + 32);
        shortx8 Vn = negf(Vi);
        #pragma unroll
        for (int qt = 0; qt < 2; ++qt) {
            const ushort* ab = &A1[(qt*16 + l15) * ASTR2 + quad * 8];
            const ushort* pb = &P1[(qt*16 + l15) * ASTR2 + quad * 8];
            shortx8 Aa0 = *(const shortx8*)(ab);
            shortx8 Aa1 = *(const shortx8*)(ab + 32);
            shortx8 Pa0 = *(const shortx8*)(pb);
            shortx8 Pa1 = *(const shortx8*)(pb + 32);
            accAor[qt] = MFMA16(Aa0, Vr, accAor[qt]); accAor[qt] = MFMA16(Aa1, Vn, accAor[qt]);
            accAoi[qt] = MFMA16(Aa1, Vr, accAoi[qt]); accAoi[qt] = MFMA16(Aa0, Vi, accAoi[qt]);
            accPor[qt] = MFMA16(Pa0, Vr, accPor[qt]); accPor[qt] = MFMA16(Pa1, Vn, accPor[qt]);
            accPoi[qt] = MFMA16(Pa1, Vr, accPoi[qt]); accPoi[qt] = MFMA16(Pa0, Vi, accPoi[qt]);
        }
    }

    // ---- combine per-row min/max (2 waves share each q row) ----
    #pragma unroll
    for (int r = 0; r < 4; ++r) {
        float mn = rmn[r], mx = rmx[r];
        #pragma unroll
        for (int o = 1; o < 16; o <<= 1) {
            mn = fminf(mn, __shfl_xor(mn, o));
            mx = fmaxf(mx, __shfl_xor(mx, o));
        }
        if (l15 == 0) {
            const int q = qt_w*16 + quad*4 + r;
            atomicMin(&mnb[q], __float_as_uint(mn));   // mag >= 0: bits monotone
            atomicMax(&mxb[q], __float_as_uint(mx));
        }
    }
    __syncthreads();

    // ---- epilogue: o = (A - mn*P)/(mx - mn) ----
    #pragma unroll
    for (int qt = 0; qt < 2; ++qt) {
        #pragma unroll
        for (int r = 0; r < 4; ++r) {
            const int q = qt*16 + quad*4 + r;
            const float mn = __uint_as_float(mnb[q]);
            const float mx = __uint_as_float(mxb[q]);
            const float d = mx - mn;
            const float invd = d > 0.f ? 1.f / d : 0.f;
            const size_t off = (qrow0 + q) * DD + h * 64 + wave*16 + l15;
            o_r[off] = (accAor[qt][r] - mn * accPor[qt][r]) * invd;
            o_i[off] = (accAoi[qt][r] - mn * accPoi[qt][r]) * invd;
        }
    }
}

// ---------------------------------------------------------------------------
// Complex covariance-whitening layernorm, one wave per (b,s) row.
// ---------------------------------------------------------------------------
__global__ __launch_bounds__(256) void ln_kernel(
    const float* __restrict__ xr, const float* __restrict__ xi,
    const float* __restrict__ g_rr, const float* __restrict__ g_ri,
    const float* __restrict__ g_ii,
    const float* __restrict__ b_r, const float* __restrict__ b_i,
    float* __restrict__ out)
{
    const int lane = threadIdx.x & 63;
    const int wave = threadIdx.x >> 6;
    const int row  = blockIdx.x * 4 + wave;
    const float* pr = xr + (size_t)row * DD;
    const float* pi = xi + (size_t)row * DD;

    float r[16], im[16];
    float sr = 0.f, si = 0.f;
    #pragma unroll
    for (int j = 0; j < 16; ++j) {
        r[j]  = pr[lane + 64*j];
        im[j] = pi[lane + 64*j];
        sr += r[j]; si += im[j];
    }
    #pragma unroll
    for (int o = 32; o; o >>= 1) { sr += __shfl_xor(sr, o); si += __shfl_xor(si, o); }
    const float mr = sr * (1.f / DD), mi = si * (1.f / DD);

    float srr = 0.f, sii = 0.f, sri = 0.f;
    #pragma unroll
    for (int j = 0; j < 16; ++j) {
        const float a = r[j] - mr, c = im[j] - mi;
        srr = fmaf(a, a, srr); sii = fmaf(c, c, sii); sri = fmaf(a, c, sri);
    }
    #pragma unroll
    for (int o = 32; o; o >>= 1) {
        srr += __shfl_xor(srr, o); sii += __shfl_xor(sii, o); sri += __shfl_xor(sri, o);
    }
    const float Vrr = srr * (1.f / DD) + EPS_LN;
    const float Vii = sii * (1.f / DD) + EPS_LN;
    const float Vri = sri * (1.f / DD);
    const float s  = sqrtf(Vrr * Vii - Vri * Vri);
    const float t  = sqrtf(Vrr + Vii + 2.f * s);
    const float inv = 1.f / (s * t);
    const float Wrr = (Vii + s) * inv;
    const float Wii = (Vrr + s) * inv;
    const float Wri = -Vri * inv;

    #pragma unroll
    for (int j = 0; j < 16; ++j) {
        const int d = lane + 64*j;
        const float a = r[j] - mr, c = im[j] - mi;
        const float or_ = Wrr * a + Wri * c;
        const float oi_ = Wri * a + Wii * c;
        out[(size_t)row * DD + d] = g_rr[d]*or_ + g_ri[d]*oi_ + b_r[d];
        out[(size_t)(M_ROWS) * DD + (size_t)row * DD + d] = g_ri[d]*or_ + g_ii[d]*oi_ + b_i[d];
    }
}

// ---------------------------------------------------------------------------
extern "C" void kernel_launch(void* const* d_in, const int* in_sizes, int n_in,
                              void* d_out, int out_size, void* d_ws, size_t ws_size,
                              hipStream_t stream) {
    const float* q_r  = (const float*)d_in[0];
    const float* q_i  = (const float*)d_in[1];
    const float* k_r  = (const float*)d_in[2];
    const float* k_i  = (const float*)d_in[3];
    const float* v_r  = (const float*)d_in[4];
    const float* v_i  = (const float*)d_in[5];
    const float* wq_r = (const float*)d_in[6];
    const float* wq_i = (const float*)d_in[7];
    const float* wk_r = (const float*)d_in[8];
    const float* wk_i = (const float*)d_in[9];
    const float* wv_r = (const float*)d_in[10];
    const float* wv_i = (const float*)d_in[11];
    const float* fc_r = (const float*)d_in[12];
    const float* fc_i = (const float*)d_in[13];
    const float* g_rr = (const float*)d_in[14];
    const float* g_ri = (const float*)d_in[15];
    const float* g_ii = (const float*)d_in[16];
    const float* b_r  = (const float*)d_in[17];
    const float* b_i  = (const float*)d_in[18];
    float* out = (float*)d_out;

    float* ws = (float*)d_ws;
    const size_t NE = (size_t)M_ROWS * N_COLS;
    float* opr = ws + 0*NE;
    float* opi = ws + 1*NE;
    float* fr  = ws + 2*NE;
    float* fi  = ws + 3*NE;
    ushort* qpk = (ushort*)(ws + 4*NE);   // [4096][16][128] bf16
    ushort* kpk = (ushort*)(ws + 5*NE);   // [4096][16][128] bf16
    ushort* vpk = (ushort*)(ws + 6*NE);   // [(b*16+h)*64+dv][2048] bf16

    const dim3 gblk(N_COLS / 64, M_ROWS / 64);  // (16, 64)

    // projections -> bf16 packs (q gets 1/sqrt(DK) folded in)
    cgemm_nt<<<gblk, 256, 0, stream>>>(q_r, q_i, wq_r, wq_i, nullptr, nullptr, qpk, 0.125f, nullptr, nullptr, 1);
    cgemm_nt<<<gblk, 256, 0, stream>>>(k_r, k_i, wk_r, wk_i, nullptr, nullptr, kpk, 1.0f,  nullptr, nullptr, 1);
    cgemm_nt<<<gblk, 256, 0, stream>>>(v_r, v_i, wv_r, wv_i, nullptr, nullptr, vpk, 1.0f,  nullptr, nullptr, 2);

    // fused MFMA attention + MagMinMaxNorm
    attn_mfma<<<dim3(SS/32, HH, BB), 256, 0, stream>>>(qpk, kpk, vpk, opr, opi);

    // output projection + residual (fp32)
    cgemm_nt<<<gblk, 256, 0, stream>>>(opr, opi, fc_r, fc_i, fr, fi, nullptr, 1.0f, q_r, q_i, 0);

    // complex layernorm -> d_out [2,B,S,D]
    ln_kernel<<<M_ROWS / 4, 256, 0, stream>>>(fr, fi, g_rr, g_ri, g_ii, b_r, b_i, out);
}

// Round 3
// 664.072 us; speedup vs baseline: 5.6903x; 3.0302x over previous
//
#include <hip/hip_runtime.h>
#include <hip/hip_bf16.h>

// Problem constants
#define BB 4
#define SS 1024
#define DD 1024
#define HH 16
#define DKH 64
#define EPS_LN 1e-6f

#define M_ROWS 4096   // B*S
#define KK 2048       // concatenated complex K (re|im)

typedef float  floatx4 __attribute__((ext_vector_type(4)));
typedef short  shortx8 __attribute__((ext_vector_type(8)));
#define MFMA16(a, b, c) __builtin_amdgcn_mfma_f32_16x16x32_bf16(a, b, c, 0, 0, 0)

// float -> bf16 (RNE) bit pattern
__device__ __forceinline__ ushort f2b(float x) {
    union { float f; unsigned u; } a; a.f = x;
    unsigned r = (a.u + 0x7fffu + ((a.u >> 16) & 1u)) >> 16;
    return (ushort)r;
}

// negate a bf16x8 fragment (flip sign bits)
__device__ __forceinline__ shortx8 negf(shortx8 x) {
    shortx8 r;
    #pragma unroll
    for (int i = 0; i < 8; ++i) r[i] = (short)(x[i] ^ (short)0x8000);
    return r;
}

// async global->LDS, 16 bytes per lane (lane-contiguous LDS layout required)
__device__ __forceinline__ void gl16(const void* g, void* l) {
    __builtin_amdgcn_global_load_lds(
        (const __attribute__((address_space(1))) unsigned int*)g,
        (__attribute__((address_space(3))) unsigned int*)l, 16, 0, 0);
}

// ---------------------------------------------------------------------------
// pack_x: [4096][1024] fp32 pair -> [4096][2048] bf16  (row = [re | im])
// blockIdx.y selects tensor (q,k,v)
// ---------------------------------------------------------------------------
__global__ __launch_bounds__(256) void pack_x(
    const float* __restrict__ qr, const float* __restrict__ qi,
    const float* __restrict__ kr, const float* __restrict__ ki,
    const float* __restrict__ vr, const float* __restrict__ vi,
    ushort* __restrict__ Xq, ushort* __restrict__ Xk, ushort* __restrict__ Xv)
{
    const int t = blockIdx.y;
    const float* pr = t == 0 ? qr : t == 1 ? kr : vr;
    const float* pi = t == 0 ? qi : t == 1 ? ki : vi;
    ushort* X = t == 0 ? Xq : t == 1 ? Xk : Xv;
    const int idx = blockIdx.x * 256 + threadIdx.x;   // [0, 4096*256)
    const int row = idx >> 8, c4 = (idx & 255) * 4;
    float4 a = *(const float4*)(pr + (size_t)row * 1024 + c4);
    float4 b = *(const float4*)(pi + (size_t)row * 1024 + c4);
    ushort4 ua; ua.x = f2b(a.x); ua.y = f2b(a.y); ua.z = f2b(a.z); ua.w = f2b(a.w);
    ushort4 ub; ub.x = f2b(b.x); ub.y = f2b(b.y); ub.z = f2b(b.z); ub.w = f2b(b.w);
    *(ushort4*)(X + (size_t)row * KK + c4)        = ua;
    *(ushort4*)(X + (size_t)row * KK + 1024 + c4) = ub;
}

// ---------------------------------------------------------------------------
// pack_w: [1024][1024] fp32 pair -> [2048][2048] bf16
//   row n       = [ wr[n] | -wi[n] ]   (produces Yr)
//   row 1024+n  = [ wi[n] |  wr[n] ]   (produces Yi)
// blockIdx.y selects pair (wq, wk, wv, fc)
// ---------------------------------------------------------------------------
__global__ __launch_bounds__(256) void pack_w(
    const float* __restrict__ ar, const float* __restrict__ ai,
    const float* __restrict__ br, const float* __restrict__ bi,
    const float* __restrict__ cr, const float* __restrict__ ci,
    const float* __restrict__ dr, const float* __restrict__ di,
    ushort* __restrict__ Bq, ushort* __restrict__ Bk,
    ushort* __restrict__ Bv, ushort* __restrict__ Bf)
{
    const int t = blockIdx.y;
    const float* wr = t == 0 ? ar : t == 1 ? br : t == 2 ? cr : dr;
    const float* wi = t == 0 ? ai : t == 1 ? bi : t == 2 ? ci : di;
    ushort* Bo = t == 0 ? Bq : t == 1 ? Bk : t == 2 ? Bv : Bf;
    const int idx = blockIdx.x * 256 + threadIdx.x;   // [0, 1024*256)
    const int n = idx >> 8, c4 = (idx & 255) * 4;
    float4 a = *(const float4*)(wr + (size_t)n * 1024 + c4);
    float4 b = *(const float4*)(wi + (size_t)n * 1024 + c4);
    ushort4 ua; ua.x = f2b(a.x);  ua.y = f2b(a.y);  ua.z = f2b(a.z);  ua.w = f2b(a.w);
    ushort4 ub; ub.x = f2b(b.x);  ub.y = f2b(b.y);  ub.z = f2b(b.z);  ub.w = f2b(b.w);
    ushort4 un; un.x = f2b(-b.x); un.y = f2b(-b.y); un.z = f2b(-b.z); un.w = f2b(-b.w);
    *(ushort4*)(Bo + (size_t)n * KK + c4)                 = ua;
    *(ushort4*)(Bo + (size_t)n * KK + 1024 + c4)          = un;
    *(ushort4*)(Bo + (size_t)(1024 + n) * KK + c4)        = ub;
    *(ushort4*)(Bo + (size_t)(1024 + n) * KK + 1024 + c4) = ua;
}

// ---------------------------------------------------------------------------
// bf16 MFMA GEMM (m97 recipe): C[M=4096, N=2048] = A[M,2048] . B[N,2048]^T
// 128x128 tile, BK=32, 256 threads (4 waves, each 64x64), global_load_lds.
// Epilogue modes:
//   0: QK pack  [m][h][re64|im64] bf16  (scale applied)
//   1: V pack   [(b*16+h)*64+dv][t*64 + (s&31) (+32 im)] bf16
//   2: fp32 out + residual: out0=fr, out1=fi (+ resr/resi)
// ---------------------------------------------------------------------------
#define BM 128
#define BN 128
#define BK 32

__global__ __launch_bounds__(256) void bgemm_nt(
    const ushort* __restrict__ A, const ushort* __restrict__ Bm,
    void* __restrict__ out0, void* __restrict__ out1,
    const float* __restrict__ resr, const float* __restrict__ resi,
    float scale, int mode)
{
    __shared__ __align__(16) ushort As[BM * BK];
    __shared__ __align__(16) ushort Bs[BN * BK];

    const int tid = threadIdx.x;
    const int lane = tid & 63, wave = tid >> 6;
    const int l15 = lane & 15, quad = lane >> 4;
    const int m0 = blockIdx.y * BM, n0 = blockIdx.x * BN;
    const int wm = (wave & 1) * 64, wn = (wave >> 1) * 64;

    const int id0 = tid, id1 = 256 + tid;
    const ushort* ga0 = A  + (size_t)(m0 + (id0 >> 2)) * KK + (id0 & 3) * 8;
    const ushort* ga1 = A  + (size_t)(m0 + (id1 >> 2)) * KK + (id1 & 3) * 8;
    const ushort* gb0 = Bm + (size_t)(n0 + (id0 >> 2)) * KK + (id0 & 3) * 8;
    const ushort* gb1 = Bm + (size_t)(n0 + (id1 >> 2)) * KK + (id1 & 3) * 8;
    ushort* la0 = &As[id0 * 8];
    ushort* la1 = &As[id1 * 8];
    ushort* lb0 = &Bs[id0 * 8];
    ushort* lb1 = &Bs[id1 * 8];

    floatx4 acc[4][4];
    #pragma unroll
    for (int fm = 0; fm < 4; ++fm)
        #pragma unroll
        for (int fn = 0; fn < 4; ++fn)
            acc[fm][fn] = (floatx4){0.f, 0.f, 0.f, 0.f};

    for (int k0 = 0; k0 < KK; k0 += BK) {
        gl16(ga0 + k0, la0);
        gl16(ga1 + k0, la1);
        gl16(gb0 + k0, lb0);
        gl16(gb1 + k0, lb1);
        __syncthreads();   // drains vmcnt: staging complete

        shortx8 af[4], bf[4];
        #pragma unroll
        for (int f = 0; f < 4; ++f)
            af[f] = *(const shortx8*)&As[(wm + f * 16 + l15) * BK + quad * 8];
        #pragma unroll
        for (int f = 0; f < 4; ++f)
            bf[f] = *(const shortx8*)&Bs[(wn + f * 16 + l15) * BK + quad * 8];
        #pragma unroll
        for (int fm = 0; fm < 4; ++fm)
            #pragma unroll
            for (int fn = 0; fn < 4; ++fn)
                acc[fm][fn] = MFMA16(af[fm], bf[fn], acc[fm][fn]);
        __syncthreads();   // all LDS reads done before next staging
    }

    // Epilogue. C layout: col = lane&15, row = quad*4 + reg.
    #pragma unroll
    for (int fm = 0; fm < 4; ++fm) {
        #pragma unroll
        for (int fn = 0; fn < 4; ++fn) {
            #pragma unroll
            for (int r = 0; r < 4; ++r) {
                const int m = m0 + wm + fm * 16 + quad * 4 + r;
                const int n = n0 + wn + fn * 16 + l15;
                const float v = acc[fm][fn][r] * scale;
                if (mode == 0) {
                    const int re = n < 1024 ? 0 : 64;
                    const int nn = n & 1023, h = nn >> 6, d = nn & 63;
                    ((ushort*)out0)[(size_t)m * KK + h * 128 + re + d] = f2b(v);
                } else if (mode == 1) {
                    const int re = n < 1024 ? 0 : 32;
                    const int nn = n & 1023, h = nn >> 6, dv = nn & 63;
                    const int bb = m >> 10, s = m & 1023;
                    ((ushort*)out0)[((size_t)((bb * HH + h) * 64 + dv)) * KK
                                    + (s >> 5) * 64 + (s & 31) + re] = f2b(v);
                } else {
                    const int nn = n & 1023;
                    const size_t off = (size_t)m * 1024 + nn;
                    if (n < 1024) ((float*)out0)[off] = v + resr[off];
                    else          ((float*)out1)[off] = v + resi[off];
                }
            }
        }
    }
}

// ---------------------------------------------------------------------------
// MFMA attention + exact streamed MagMinMaxNorm.
//   o = (A - mn*P)/(mx - mn);  A = sum attn*v,  P = sum (attn/|attn|)*v
// Output: bf16 pack xo[m][2048] = [o_r (h*64+dv) | o_i].
// ---------------------------------------------------------------------------
#define ASTR2 88   // bf16 stride: 176B rows -> 16B-aligned b128 reads

__global__ __launch_bounds__(256) void attn_mfma(
    const ushort* __restrict__ qpk, const ushort* __restrict__ kpk,
    const ushort* __restrict__ vpk, ushort* __restrict__ xo)
{
    __shared__ __align__(16) ushort A1[32 * ASTR2];
    __shared__ __align__(16) ushort P1[32 * ASTR2];
    __shared__ unsigned mnb[32], mxb[32];

    const int tid  = threadIdx.x;
    const int wave = tid >> 6, lane = tid & 63;
    const int l15  = lane & 15, quad = lane >> 4;
    const int qt_w = wave & 1, kt_w = wave >> 1;
    const int qtile = blockIdx.x, h = blockIdx.y, b = blockIdx.z;
    const size_t qrow0 = (size_t)b * SS + (size_t)qtile * 32;

    if (tid < 32) { mnb[tid] = 0x7f800000u; mxb[tid] = 0u; }

    const ushort* qb = qpk + (qrow0 + qt_w * 16 + l15) * KK + h * 128 + quad * 8;
    shortx8 Aq[4];
    #pragma unroll
    for (int f = 0; f < 4; ++f) Aq[f] = *(const shortx8*)(qb + f * 32);

    floatx4 accAor[2], accAoi[2], accPor[2], accPoi[2];
    #pragma unroll
    for (int qt = 0; qt < 2; ++qt) {
        accAor[qt] = (floatx4){0.f,0.f,0.f,0.f};
        accAoi[qt] = (floatx4){0.f,0.f,0.f,0.f};
        accPor[qt] = (floatx4){0.f,0.f,0.f,0.f};
        accPoi[qt] = (floatx4){0.f,0.f,0.f,0.f};
    }
    float rmn[4] = {1e30f,1e30f,1e30f,1e30f};
    float rmx[4] = {0.f,0.f,0.f,0.f};

    const ushort* kb0 = kpk + ((size_t)b * SS + kt_w * 16 + l15) * KK + h * 128 + quad * 8;
    const ushort* vb0 = vpk + (((size_t)(b * HH + h)) * 64 + wave * 16 + l15) * KK + quad * 8;

    for (int kt0 = 0; kt0 < SS; kt0 += 32) {
        const ushort* kb = kb0 + (size_t)kt0 * KK;
        shortx8 K0 = *(const shortx8*)(kb);
        shortx8 K1 = *(const shortx8*)(kb + 32);
        shortx8 K2 = *(const shortx8*)(kb + 64);
        shortx8 K3 = *(const shortx8*)(kb + 96);
        shortx8 N2 = negf(K2), N3 = negf(K3);
        floatx4 cr = (floatx4){0.f,0.f,0.f,0.f};
        floatx4 ci = (floatx4){0.f,0.f,0.f,0.f};
        cr = MFMA16(Aq[0], K0, cr); cr = MFMA16(Aq[1], K1, cr);
        cr = MFMA16(Aq[2], N2, cr); cr = MFMA16(Aq[3], N3, cr);   // qr·kr − qi·ki
        ci = MFMA16(Aq[2], K0, ci); ci = MFMA16(Aq[3], K1, ci);
        ci = MFMA16(Aq[0], K2, ci); ci = MFMA16(Aq[1], K3, ci);   // qi·kr + qr·ki

        __syncthreads();
        #pragma unroll
        for (int r = 0; r < 4; ++r) {
            const float ar = cr[r], ai = ci[r];
            const float mag = sqrtf(fmaf(ar, ar, ai * ai));
            const float im  = mag > 0.f ? 1.f / mag : 0.f;
            rmn[r] = fminf(rmn[r], mag);
            rmx[r] = fmaxf(rmx[r], mag);
            const int q = qt_w * 16 + quad * 4 + r;
            const int k = kt_w * 16 + l15;
            A1[q * ASTR2 + k]      = f2b(ar);
            A1[q * ASTR2 + 32 + k] = f2b(ai);
            P1[q * ASTR2 + k]      = f2b(ar * im);
            P1[q * ASTR2 + 32 + k] = f2b(ai * im);
        }
        __syncthreads();

        const ushort* vb = vb0 + (kt0 >> 5) * 64;
        shortx8 Vr = *(const shortx8*)(vb);
        shortx8 Vi = *(const shortx8*)(vb + 32);
        shortx8 Vn = negf(Vi);
        #pragma unroll
        for (int qt = 0; qt < 2; ++qt) {
            const ushort* ab = &A1[(qt * 16 + l15) * ASTR2 + quad * 8];
            const ushort* pb = &P1[(qt * 16 + l15) * ASTR2 + quad * 8];
            shortx8 Aa0 = *(const shortx8*)(ab);
            shortx8 Aa1 = *(const shortx8*)(ab + 32);
            shortx8 Pa0 = *(const shortx8*)(pb);
            shortx8 Pa1 = *(const shortx8*)(pb + 32);
            accAor[qt] = MFMA16(Aa0, Vr, accAor[qt]); accAor[qt] = MFMA16(Aa1, Vn, accAor[qt]);
            accAoi[qt] = MFMA16(Aa1, Vr, accAoi[qt]); accAoi[qt] = MFMA16(Aa0, Vi, accAoi[qt]);
            accPor[qt] = MFMA16(Pa0, Vr, accPor[qt]); accPor[qt] = MFMA16(Pa1, Vn, accPor[qt]);
            accPoi[qt] = MFMA16(Pa1, Vr, accPoi[qt]); accPoi[qt] = MFMA16(Pa0, Vi, accPoi[qt]);
        }
    }

    #pragma unroll
    for (int r = 0; r < 4; ++r) {
        float mn = rmn[r], mx = rmx[r];
        #pragma unroll
        for (int o = 1; o < 16; o <<= 1) {
            mn = fminf(mn, __shfl_xor(mn, o));
            mx = fmaxf(mx, __shfl_xor(mx, o));
        }
        if (l15 == 0) {
            const int q = qt_w * 16 + quad * 4 + r;
            atomicMin(&mnb[q], __float_as_uint(mn));
            atomicMax(&mxb[q], __float_as_uint(mx));
        }
    }
    __syncthreads();

    #pragma unroll
    for (int qt = 0; qt < 2; ++qt) {
        #pragma unroll
        for (int r = 0; r < 4; ++r) {
            const int q = qt * 16 + quad * 4 + r;
            const float mn = __uint_as_float(mnb[q]);
            const float mx = __uint_as_float(mxb[q]);
            const float d = mx - mn;
            const float invd = d > 0.f ? 1.f / d : 0.f;
            const float vr_ = (accAor[qt][r] - mn * accPor[qt][r]) * invd;
            const float vi_ = (accAoi[qt][r] - mn * accPoi[qt][r]) * invd;
            const size_t rowo = (qrow0 + q) * KK + h * 64 + wave * 16 + l15;
            xo[rowo]        = f2b(vr_);
            xo[rowo + 1024] = f2b(vi_);
        }
    }
}

// ---------------------------------------------------------------------------
// Complex covariance-whitening layernorm, one wave per (b,s) row.
// ---------------------------------------------------------------------------
__global__ __launch_bounds__(256) void ln_kernel(
    const float* __restrict__ xr, const float* __restrict__ xi,
    const float* __restrict__ g_rr, const float* __restrict__ g_ri,
    const float* __restrict__ g_ii,
    const float* __restrict__ b_r, const float* __restrict__ b_i,
    float* __restrict__ out)
{
    const int lane = threadIdx.x & 63;
    const int wave = threadIdx.x >> 6;
    const int row  = blockIdx.x * 4 + wave;
    const float* pr = xr + (size_t)row * DD;
    const float* pi = xi + (size_t)row * DD;

    float r[16], im[16];
    float sr = 0.f, si = 0.f;
    #pragma unroll
    for (int j = 0; j < 16; ++j) {
        r[j]  = pr[lane + 64*j];
        im[j] = pi[lane + 64*j];
        sr += r[j]; si += im[j];
    }
    #pragma unroll
    for (int o = 32; o; o >>= 1) { sr += __shfl_xor(sr, o); si += __shfl_xor(si, o); }
    const float mr = sr * (1.f / DD), mi = si * (1.f / DD);

    float srr = 0.f, sii = 0.f, sri = 0.f;
    #pragma unroll
    for (int j = 0; j < 16; ++j) {
        const float a = r[j] - mr, c = im[j] - mi;
        srr = fmaf(a, a, srr); sii = fmaf(c, c, sii); sri = fmaf(a, c, sri);
    }
    #pragma unroll
    for (int o = 32; o; o >>= 1) {
        srr += __shfl_xor(srr, o); sii += __shfl_xor(sii, o); sri += __shfl_xor(sri, o);
    }
    const float Vrr = srr * (1.f / DD) + EPS_LN;
    const float Vii = sii * (1.f / DD) + EPS_LN;
    const float Vri = sri * (1.f / DD);
    const float s  = sqrtf(Vrr * Vii - Vri * Vri);
    const float t  = sqrtf(Vrr + Vii + 2.f * s);
    const float inv = 1.f / (s * t);
    const float Wrr = (Vii + s) * inv;
    const float Wii = (Vrr + s) * inv;
    const float Wri = -Vri * inv;

    #pragma unroll
    for (int j = 0; j < 16; ++j) {
        const int d = lane + 64*j;
        const float a = r[j] - mr, c = im[j] - mi;
        const float or_ = Wrr * a + Wri * c;
        const float oi_ = Wri * a + Wii * c;
        out[(size_t)row * DD + d] = g_rr[d]*or_ + g_ri[d]*oi_ + b_r[d];
        out[(size_t)(M_ROWS) * DD + (size_t)row * DD + d] = g_ri[d]*or_ + g_ii[d]*oi_ + b_i[d];
    }
}

// ---------------------------------------------------------------------------
extern "C" void kernel_launch(void* const* d_in, const int* in_sizes, int n_in,
                              void* d_out, int out_size, void* d_ws, size_t ws_size,
                              hipStream_t stream) {
    const float* q_r  = (const float*)d_in[0];
    const float* q_i  = (const float*)d_in[1];
    const float* k_r  = (const float*)d_in[2];
    const float* k_i  = (const float*)d_in[3];
    const float* v_r  = (const float*)d_in[4];
    const float* v_i  = (const float*)d_in[5];
    const float* wq_r = (const float*)d_in[6];
    const float* wq_i = (const float*)d_in[7];
    const float* wk_r = (const float*)d_in[8];
    const float* wk_i = (const float*)d_in[9];
    const float* wv_r = (const float*)d_in[10];
    const float* wv_i = (const float*)d_in[11];
    const float* fc_r = (const float*)d_in[12];
    const float* fc_i = (const float*)d_in[13];
    const float* g_rr = (const float*)d_in[14];
    const float* g_ri = (const float*)d_in[15];
    const float* g_ii = (const float*)d_in[16];
    const float* b_r  = (const float*)d_in[17];
    const float* b_i  = (const float*)d_in[18];
    float* out = (float*)d_out;

    // Workspace layout: 8 units of NE floats (16 MiB) = 128 MiB total.
    float* ws = (float*)d_ws;
    const size_t NE = (size_t)M_ROWS * 1024;        // 4M floats = 16 MiB
    ushort* Xq  = (ushort*)(ws + 0 * NE);           // u0; later fr
    ushort* Xk  = (ushort*)(ws + 1 * NE);           // u1; later fi
    ushort* Xv  = (ushort*)(ws + 2 * NE);           // u2; later xo
    ushort* qpk = (ushort*)(ws + 3 * NE);           // u3
    ushort* kpk = (ushort*)(ws + 4 * NE);           // u4
    ushort* vpk = (ushort*)(ws + 5 * NE);           // u5
    ushort* Bq  = (ushort*)(ws + 6 * NE);           // u6 lo
    ushort* Bk  = Bq + (size_t)KK * KK;             // u6 hi
    ushort* Bv  = (ushort*)(ws + 7 * NE);           // u7 lo
    ushort* Bf  = Bv + (size_t)KK * KK;             // u7 hi
    float*  fr  = ws + 0 * NE;                      // aliases dead Xq
    float*  fi  = ws + 1 * NE;                      // aliases dead Xk
    ushort* xo  = (ushort*)(ws + 2 * NE);           // aliases dead Xv

    // bf16 operand packing
    pack_x<<<dim3(4096, 3), 256, 0, stream>>>(q_r, q_i, k_r, k_i, v_r, v_i, Xq, Xk, Xv);
    pack_w<<<dim3(1024, 4), 256, 0, stream>>>(wq_r, wq_i, wk_r, wk_i, wv_r, wv_i,
                                              fc_r, fc_i, Bq, Bk, Bv, Bf);

    const dim3 gg(KK / BN, M_ROWS / BM);  // (16, 32) = 512 blocks

    // projections -> attention packs (q gets 1/sqrt(DK) folded in)
    bgemm_nt<<<gg, 256, 0, stream>>>(Xq, Bq, qpk, nullptr, nullptr, nullptr, 0.125f, 0);
    bgemm_nt<<<gg, 256, 0, stream>>>(Xk, Bk, kpk, nullptr, nullptr, nullptr, 1.0f,  0);
    bgemm_nt<<<gg, 256, 0, stream>>>(Xv, Bv, vpk, nullptr, nullptr, nullptr, 1.0f,  1);

    // fused MFMA attention + MagMinMaxNorm -> bf16 [4096][2048] pack
    attn_mfma<<<dim3(SS / 32, HH, BB), 256, 0, stream>>>(qpk, kpk, vpk, xo);

    // output projection + residual (bf16 MFMA, fp32 out)
    bgemm_nt<<<gg, 256, 0, stream>>>(xo, Bf, fr, fi, q_r, q_i, 1.0f, 2);

    // complex layernorm -> d_out [2,B,S,D]
    ln_kernel<<<M_ROWS / 4, 256, 0, stream>>>(fr, fi, g_rr, g_ri, g_ii, b_r, b_i, out);
}